// Round 5
// baseline (177.339 us; speedup 1.0000x reference)
//
#include <hip/hip_runtime.h>
#include <float.h>

using v2f = __attribute__((ext_vector_type(2))) float;
using v4f = __attribute__((ext_vector_type(4))) float;

#define EMB 10
#define STATE 20
#define HIDDEN 40
#define NPROJ 2490
#define NSPLIT 4                 // row-split waves per 128-element group

// Per-element MLP: x = [wemb[wi], pemb[pi]] -> relu(W1 x + b1) -> W2 h + b2
__device__ __forceinline__ void mlp_eval(
    const float* __restrict__ wr, const float* __restrict__ pr,
    const float* __restrict__ W1, const float* __restrict__ b1,
    const float* __restrict__ W2, const float* __restrict__ b2,
    v2f wv2[5])
{
    v2f x2[STATE / 2];
    #pragma unroll
    for (int k = 0; k < EMB / 2; ++k) x2[k] = *(const v2f*)(wr + 2 * k);
    #pragma unroll
    for (int k = 0; k < EMB / 2; ++k) x2[EMB / 2 + k] = *(const v2f*)(pr + 2 * k);

    float hb[HIDDEN];
    #pragma unroll 4
    for (int j = 0; j < HIDDEN; ++j) {       // W1/b1 uniform -> scalar loads
        const v2f* w1r = (const v2f*)(W1 + j * STATE);
        v2f a = w1r[0] * x2[0];
        #pragma unroll
        for (int k = 1; k < STATE / 2; ++k) a += w1r[k] * x2[k];
        hb[j] = fmaxf(a.x + a.y + b1[j], 0.0f);
    }
    v2f h2[HIDDEN / 2];
    #pragma unroll
    for (int k = 0; k < HIDDEN / 2; ++k) h2[k] = (v2f){hb[2 * k], hb[2 * k + 1]};

    #pragma unroll
    for (int d = 0; d < EMB; d += 2) {
        const v2f* w2r0 = (const v2f*)(W2 + d * HIDDEN);
        const v2f* w2r1 = (const v2f*)(W2 + (d + 1) * HIDDEN);
        v2f a0 = w2r0[0] * h2[0];
        v2f a1 = w2r1[0] * h2[0];
        #pragma unroll
        for (int k = 1; k < HIDDEN / 2; ++k) { a0 += w2r0[k] * h2[k]; a1 += w2r1[k] * h2[k]; }
        wv2[d / 2] = (v2f){a0.x + a0.y + b2[d], a1.x + a1.y + b2[d + 1]};
    }
}

// Single row score (for the lone row 1)
__device__ __forceinline__ float dot_row(const float* __restrict__ row, const v2f wv[5]) {
    v2f c0 = *(const v2f*)(row + 0);
    v4f c1 = *(const v4f*)(row + 2);
    v4f c2 = *(const v4f*)(row + 6);
    v2f a = wv[0] * c0;
    a += wv[1] * c1.lo; a += wv[2] * c1.hi;
    a += wv[3] * c2.lo; a += wv[4] * c2.hi;
    return a.x + a.y;
}

// One even row-pair (rows 2p, 2p+1) scored against TWO elements' weights.
// tbl4 indexed only by uniform p -> s_load_dwordx4 (SGPR data, wave-uniform).
__device__ __forceinline__ void score_pair2(const v4f* __restrict__ tbl4, int p,
                                            const v2f wva[5], const v2f wvb[5],
                                            float& ba, int& ia, float& bb, int& ib) {
    const v4f* tp = tbl4 + p * 5;
    v4f a0 = tp[0], a1 = tp[1], a2 = tp[2], a3 = tp[3], a4 = tp[4];
    // element A
    v2f c0 = wva[0] * a0.lo;
    c0 += wva[1] * a0.hi; c0 += wva[2] * a1.lo;
    c0 += wva[3] * a1.hi; c0 += wva[4] * a2.lo;
    float s0 = c0.x + c0.y;
    v2f c1 = wva[0] * a2.hi;
    c1 += wva[1] * a3.lo; c1 += wva[2] * a3.hi;
    c1 += wva[3] * a4.lo; c1 += wva[4] * a4.hi;
    float s1 = c1.x + c1.y;
    float sp = s0; int ip = 2 * p;
    if (s1 > sp) { sp = s1; ip = 2 * p + 1; }   // strict > : earlier index wins ties
    if (sp > ba) { ba = sp; ia = ip; }
    // element B
    v2f d0 = wvb[0] * a0.lo;
    d0 += wvb[1] * a0.hi; d0 += wvb[2] * a1.lo;
    d0 += wvb[3] * a1.hi; d0 += wvb[4] * a2.lo;
    float t0 = d0.x + d0.y;
    v2f d1 = wvb[0] * a2.hi;
    d1 += wvb[1] * a3.lo; d1 += wvb[2] * a3.hi;
    d1 += wvb[3] * a4.lo; d1 += wvb[4] * a4.hi;
    float t1 = d1.x + d1.y;
    float tp2 = t0; int jp = 2 * p;
    if (t1 > tp2) { tp2 = t1; jp = 2 * p + 1; }
    if (tp2 > bb) { bb = tp2; ib = jp; }
}

__global__ __launch_bounds__(256, 2) void actor_kernel(
    const int* __restrict__ wid, const int* __restrict__ pid,
    const float* __restrict__ wemb, const float* __restrict__ pemb,
    const float* __restrict__ W1, const float* __restrict__ b1,
    const float* __restrict__ W2, const float* __restrict__ b2,
    int* __restrict__ out)
{
    __shared__ float sb[NSPLIT][2][64];
    __shared__ int   si[NSPLIT][2][64];

    const int tid  = threadIdx.x;
    const int lane = tid & 63;
    const int h    = tid >> 6;             // row-split worker 0..3
    const int b0   = blockIdx.x * 128 + lane;
    const int b1i  = b0 + 64;

    const v4f* __restrict__ tbl4 = (const v4f*)__builtin_assume_aligned(pemb, 16);

    // ---- MLP for both elements (redundant across the 4 waves; lane-identical) ----
    v2f wva[5], wvb[5];
    mlp_eval(wemb + wid[b0] * EMB, pemb + pid[b0] * EMB, W1, b1, W2, b2, wva);
    mlp_eval(wemb + wid[b1i] * EMB, pemb + pid[b1i] * EMB, W1, b1, W2, b2, wvb);

    float ba = -FLT_MAX, bb = -FLT_MAX;
    int   ia = 1, ib = 1;

    // FULL pair range [1,1245) = rows 2..2489, split 4 ways; lone row 1 -> h0.
    // (R4 bug: old table only covered pairs [1,623) = half the table.)
    const int plo[NSPLIT + 1] = {1, 312, 623, 934, 1245};
    if (h == 0) {
        ba = dot_row(pemb + 10, wva); ia = 1;
        bb = dot_row(pemb + 10, wvb); ib = 1;
    }
    const int lo = plo[h], hi = plo[h + 1];
    #pragma unroll 4
    for (int p = lo; p < hi; ++p)
        score_pair2(tbl4, p, wva, wvb, ba, ia, bb, ib);

    // ---- combine the 4 row-chunks (ascending index ranges -> strict > is exact) ----
    sb[h][0][lane] = ba; si[h][0][lane] = ia;
    sb[h][1][lane] = bb; si[h][1][lane] = ib;
    __syncthreads();
    if (h == 0) {
        #pragma unroll
        for (int k = 1; k < NSPLIT; ++k) {
            float v0 = sb[k][0][lane]; int j0 = si[k][0][lane];
            if (v0 > ba) { ba = v0; ia = j0; }
            float v1 = sb[k][1][lane]; int j1 = si[k][1][lane];
            if (v1 > bb) { bb = v1; ib = j1; }
        }
        out[b0]  = ia;
        out[b1i] = ib;
    }
}

extern "C" void kernel_launch(void* const* d_in, const int* in_sizes, int n_in,
                              void* d_out, int out_size, void* d_ws, size_t ws_size,
                              hipStream_t stream) {
    const int*   wid  = (const int*)  d_in[0];
    const int*   pid  = (const int*)  d_in[1];
    const float* wemb = (const float*)d_in[2];
    const float* pemb = (const float*)d_in[3];
    const float* W1   = (const float*)d_in[4];
    const float* b1   = (const float*)d_in[5];
    const float* W2   = (const float*)d_in[6];
    const float* b2   = (const float*)d_in[7];
    int* out = (int*)d_out;

    const int B = in_sizes[0];               // 65536
    actor_kernel<<<B / 128, 256, 0, stream>>>(wid, pid, wemb, pemb, W1, b1, W2, b2, out);
}